// Round 7
// baseline (461.683 us; speedup 1.0000x reference)
//
#include <hip/hip_runtime.h>
#include <hip/hip_fp16.h>

#define N_NODES 100000
#define N_EDGES 1600000
#define IN_F 32
#define HID 128
#define BSHIFT 9
#define BSIZE 512
#define NBUCK 196        // ceil(100000/512)
#define EPB 4096         // edges per bucket-phase block
#define NBB 391          // ceil(E/EPB)
#define REC_STRIDE 9728  // per-bucket rec capacity (mean 8163 + ~17 sigma)
#define COL_STRIDE 25600 // REC_STRIDE + 512*31 (worst pad to mult-32); mult of 32
#define ZSL 1600016      // 16-dim slice stride in fp16: (N_NODES+1)*16

typedef _Float16 half8 __attribute__((ext_vector_type(8)));
typedef float floatx4 __attribute__((ext_vector_type(4)));

// ---------------- weight pre-transpose: W*t[n][k] fp16 in global ----------------
// Wt layout: W1t [128][32] @ 0, W2t [128][128] @ 4096, W3t [32][128] @ 20480
__global__ __launch_bounds__(256) void k_wprep(const float* __restrict__ W1,
                                               const float* __restrict__ W2,
                                               const float* __restrict__ W3,
                                               _Float16* __restrict__ Wt) {
    const int bid = blockIdx.x, t = threadIdx.x;
    if (bid < 64) {               // W2: 16384 elems
        int idx = bid * 256 + t;
        int n = idx >> 7, k = idx & 127;
        Wt[4096 + idx] = (_Float16)W2[k * HID + n];
    } else if (bid < 80) {        // W1: 4096 elems
        int idx = (bid - 64) * 256 + t;
        int n = idx >> 5, k = idx & 31;
        Wt[n * 32 + k] = (_Float16)W1[k * HID + n];
    } else {                      // W3: 4096 elems
        int idx = (bid - 80) * 256 + t;
        int n = idx >> 7, k = idx & 127;
        Wt[20480 + idx] = (_Float16)W3[k * IN_F + n];
    }
}

// ---------------- CSR build (static bucket regions) ----------------

__global__ __launch_bounds__(256) void k_bucket(const int* __restrict__ src,
                                                const int* __restrict__ dst,
                                                int* __restrict__ bcur,
                                                unsigned* __restrict__ rec) {
    __shared__ int hist[256];
    __shared__ int lbase[256];
    const int e0 = blockIdx.x * EPB;
    hist[threadIdx.x] = 0;
    __syncthreads();

    unsigned rk[16]; short bk[16];
#pragma unroll
    for (int k = 0; k < 16; ++k) {
        int e = e0 + k * 256 + threadIdx.x;
        if (e < N_EDGES) {
            int d = dst[e];
            int b = d >> BSHIFT;
            bk[k] = (short)b;
            rk[k] = ((unsigned)src[e] << BSHIFT) | (unsigned)(d & (BSIZE - 1));
            atomicAdd(&hist[b], 1);
        } else bk[k] = -1;
    }
    __syncthreads();
    int c = hist[threadIdx.x];
    lbase[threadIdx.x] =
        (c > 0) ? threadIdx.x * REC_STRIDE + atomicAdd(&bcur[threadIdx.x], c) : 0;
    __syncthreads();
    hist[threadIdx.x] = 0;   // reuse as local running offset
    __syncthreads();
#pragma unroll
    for (int k = 0; k < 16; ++k) {
        if (bk[k] >= 0) {
            int off = atomicAdd(&hist[bk[k]], 1);
            rec[lbase[bk[k]] + off] = rk[k];
        }
    }
}

// per bucket: degree count + PADDED scan (rows padded to mult of 32, pads -> zero
// row N_NODES), col scatter, AND fused prescale t1 = x * dis (fp16, 2 slices).
__global__ __launch_bounds__(256) void k_fill3p(const unsigned* __restrict__ rec,
                                                const int* __restrict__ bcur,
                                                const float2* __restrict__ x2,
                                                int* __restrict__ ideg,
                                                int* __restrict__ cursor,
                                                int* __restrict__ col,
                                                _Float16* __restrict__ t1) {
    __shared__ int lcnt[BSIZE];
    __shared__ int lcur[BSIZE];
    __shared__ int lend[BSIZE];
    __shared__ int s[256];
    const int b = blockIdx.x;
    const int t = threadIdx.x;
    const int n0 = b << BSHIFT;
    const int rbeg = b * REC_STRIDE;
    const int rend = rbeg + bcur[b];
    const int pbeg = b * COL_STRIDE;   // 32-aligned

    lcnt[t] = 0;
    lcnt[t + 256] = 0;
    __syncthreads();
    for (int i = rbeg + t; i < rend; i += 256)
        atomicAdd(&lcnt[rec[i] & (BSIZE - 1)], 1);
    __syncthreads();

    int a0 = lcnt[2 * t], a1 = lcnt[2 * t + 1];
    int p0 = (a0 + 31) & ~31, p1 = (a1 + 31) & ~31;
    int pv = p0 + p1;
    s[t] = pv;
    __syncthreads();
    for (int off = 1; off < 256; off <<= 1) {
        int v = (t >= off) ? s[t - off] : 0;
        __syncthreads();
        s[t] += v;
        __syncthreads();
    }
    int ex = s[t] - pv;
    int c0 = pbeg + ex;
    int c1 = c0 + p0;
    lcur[2 * t]     = c0;  lend[2 * t]     = c0 + p0;
    lcur[2 * t + 1] = c1;  lend[2 * t + 1] = c1 + p1;
    __syncthreads();

    for (int i = t; i < BSIZE; i += 256) {
        int n = n0 + i;
        if (n < N_NODES) {
            ideg[n]   = lcnt[i];
            cursor[n] = lcur[i];
        }
    }
    __syncthreads();
    for (int i = rbeg + t; i < rend; i += 256) {
        unsigned r = rec[i];
        int slot = atomicAdd(&lcur[r & (BSIZE - 1)], 1);
        col[slot] = (int)(r >> BSHIFT);
    }
    __syncthreads();
    for (int i = t; i < BSIZE; i += 256) {
        int e2 = lend[i];
        for (int k = lcur[i]; k < e2; ++k) col[k] = N_NODES;
    }

    // fused prescale for this bucket's 512 nodes (sliced layout) + zero rows
    if (b == 0 && t < 16) {
        if (t < 8) ((unsigned*)(t1 + (size_t)N_NODES * 16))[t] = 0u;
        else       ((unsigned*)(t1 + ZSL + (size_t)N_NODES * 16))[t - 8] = 0u;
    }
    for (int idx = t; idx < BSIZE * 16; idx += 256) {
        int loc = idx >> 4, j = idx & 15;
        int n = n0 + loc;
        if (n < N_NODES) {
            float dis = rsqrtf(1.0f + (float)lcnt[loc]);
            float2 v = x2[(size_t)n * 16 + j];
            int p = j >> 3, jj = j & 7;
            *(__half2*)(t1 + (size_t)p * ZSL + (size_t)n * 16 + jj * 2) =
                __floats2half2_rn(v.x * dis, v.y * dis);
        }
    }
}

// ---------------- 32-dim gathers: 2 L2-resident slice passes ----------------
// lane = 32 slots x 2 feature-lanes (16B each); table slice = 3.2 MB < 4MB L2/XCD.

// pre: z = acc*dis, fp16 sliced out
__global__ __launch_bounds__(256) void k_gather32_pre(
    const int* __restrict__ cursor, const int* __restrict__ ideg,
    const int* __restrict__ col, const _Float16* __restrict__ T,
    _Float16* __restrict__ OUT) {
    const int lane = threadIdx.x & 63;
    const int slot = lane >> 1;
    const int fl   = lane & 1;
    const int wid  = blockIdx.x * 4 + (threadIdx.x >> 6);
    const int wstride = gridDim.x * 4;

    for (int p = 0; p < 2; ++p) {
        const _Float16* Tp = T + (size_t)p * ZSL;
        _Float16* Op = OUT + (size_t)p * ZSL;
        for (int node = wid; node < N_NODES; node += wstride) {
            int begin = cursor[node];
            int d     = ideg[node];
            int nb    = (d + 31) >> 5;
            float acc[8];
            if (slot == 0) {
                half8 v = *(const half8*)(Tp + (size_t)node * 16 + fl * 8);
#pragma unroll
                for (int i = 0; i < 8; ++i) acc[i] = (float)v[i];
            } else {
#pragma unroll
                for (int i = 0; i < 8; ++i) acc[i] = 0.f;
            }
            const int* cp = col + begin + slot;
            int itb = 0;
            for (; itb + 2 <= nb; itb += 2, cp += 64) {
                int s0 = cp[0];
                int s1 = cp[32];
                half8 v0 = *(const half8*)(Tp + (size_t)s0 * 16 + fl * 8);
                half8 v1 = *(const half8*)(Tp + (size_t)s1 * 16 + fl * 8);
#pragma unroll
                for (int i = 0; i < 8; ++i) acc[i] += (float)v0[i] + (float)v1[i];
            }
            if (itb < nb) {
                int s0 = cp[0];
                half8 v0 = *(const half8*)(Tp + (size_t)s0 * 16 + fl * 8);
#pragma unroll
                for (int i = 0; i < 8; ++i) acc[i] += (float)v0[i];
            }
#pragma unroll
            for (int m = 2; m < 64; m <<= 1)
#pragma unroll
                for (int i = 0; i < 8; ++i) acc[i] += __shfl_xor(acc[i], m, 64);
            if (slot == 0) {
                float dis = rsqrtf(1.0f + (float)d);
                half8 o;
#pragma unroll
                for (int i = 0; i < 8; ++i) o[i] = (_Float16)(acc[i] * dis);
                *(half8*)(Op + (size_t)node * 16 + fl * 8) = o;
            }
        }
    }
}

// fin: out = relu(acc*dis + b), fp32 row-major out (pass p writes cols p*16..)
__global__ __launch_bounds__(256) void k_gather32_fin(
    const int* __restrict__ cursor, const int* __restrict__ ideg,
    const int* __restrict__ col, const _Float16* __restrict__ T,
    const float* __restrict__ b, float* __restrict__ OUT) {
    const int lane = threadIdx.x & 63;
    const int slot = lane >> 1;
    const int fl   = lane & 1;
    const int wid  = blockIdx.x * 4 + (threadIdx.x >> 6);
    const int wstride = gridDim.x * 4;

    for (int p = 0; p < 2; ++p) {
        const _Float16* Tp = T + (size_t)p * ZSL;
        float4 bb0 = *(const float4*)(b + p * 16 + fl * 8);
        float4 bb1 = *(const float4*)(b + p * 16 + fl * 8 + 4);
        float bias[8] = {bb0.x, bb0.y, bb0.z, bb0.w, bb1.x, bb1.y, bb1.z, bb1.w};
        for (int node = wid; node < N_NODES; node += wstride) {
            int begin = cursor[node];
            int d     = ideg[node];
            int nb    = (d + 31) >> 5;
            float acc[8];
            if (slot == 0) {
                half8 v = *(const half8*)(Tp + (size_t)node * 16 + fl * 8);
#pragma unroll
                for (int i = 0; i < 8; ++i) acc[i] = (float)v[i];
            } else {
#pragma unroll
                for (int i = 0; i < 8; ++i) acc[i] = 0.f;
            }
            const int* cp = col + begin + slot;
            int itb = 0;
            for (; itb + 2 <= nb; itb += 2, cp += 64) {
                int s0 = cp[0];
                int s1 = cp[32];
                half8 v0 = *(const half8*)(Tp + (size_t)s0 * 16 + fl * 8);
                half8 v1 = *(const half8*)(Tp + (size_t)s1 * 16 + fl * 8);
#pragma unroll
                for (int i = 0; i < 8; ++i) acc[i] += (float)v0[i] + (float)v1[i];
            }
            if (itb < nb) {
                int s0 = cp[0];
                half8 v0 = *(const half8*)(Tp + (size_t)s0 * 16 + fl * 8);
#pragma unroll
                for (int i = 0; i < 8; ++i) acc[i] += (float)v0[i];
            }
#pragma unroll
            for (int m = 2; m < 64; m <<= 1)
#pragma unroll
                for (int i = 0; i < 8; ++i) acc[i] += __shfl_xor(acc[i], m, 64);
            if (slot == 0) {
                float dis = rsqrtf(1.0f + (float)d);
                float o[8];
#pragma unroll
                for (int i = 0; i < 8; ++i) {
                    float v = acc[i] * dis + bias[i];
                    o[i] = v > 0.f ? v : 0.f;
                }
                float* op = OUT + (size_t)node * IN_F + p * 16 + fl * 8;
                *(float4*)op       = make_float4(o[0], o[1], o[2], o[3]);
                *(float4*)(op + 4) = make_float4(o[4], o[5], o[6], o[7]);
            }
        }
    }
}

// ---------------- MFMA transforms ----------------
// 16x16x32 layouts: A[m=lane&15][k=quad*8+j], B[k=quad*8+j][n=lane&15],
// D[row=quad*4+r][col=lane&15]. Block = 4 waves x 16 rows = 64 rows.

// FUSED layers 1+2: T2 = (relu(z·W1 + b1) · W2) · dis. z is sliced [2][N+1][16].
__global__ __launch_bounds__(256, 4) void k_xform12(
    const _Float16* __restrict__ z, const _Float16* __restrict__ W1t,
    const float* __restrict__ b1, const _Float16* __restrict__ W2t,
    const int* __restrict__ ideg, _Float16* __restrict__ T) {
    if (blockIdx.x == 0 && threadIdx.x < 64)
        ((unsigned*)(T + (size_t)N_NODES * HID))[threadIdx.x] = 0u;
    __shared__ _Float16 H1s[64 * 136];

    const int lane = threadIdx.x & 63;
    const int wave = threadIdx.x >> 6;
    const int m16 = lane & 15, quad = lane >> 4;
    const int row0 = blockIdx.x * 64 + wave * 16;
    if (row0 >= N_NODES) return;

    // phase 1: H1 tile = relu(z·W1 + b1)
    {
        int arow = row0 + m16; if (arow >= N_NODES) arow = N_NODES - 1;
        half8 a = *(const half8*)(z + (size_t)(quad >> 1) * ZSL +
                                  (size_t)arow * 16 + (quad & 1) * 8);
        floatx4 acc[8];
#pragma unroll
        for (int t = 0; t < 8; ++t) acc[t] = (floatx4){0.f, 0.f, 0.f, 0.f};
#pragma unroll
        for (int t = 0; t < 8; ++t) {
            half8 bf = *(const half8*)(W1t + (t * 16 + m16) * 32 + quad * 8);
            acc[t] = __builtin_amdgcn_mfma_f32_16x16x32_f16(a, bf, acc[t], 0, 0, 0);
        }
#pragma unroll
        for (int t = 0; t < 8; ++t) {
            int c = t * 16 + m16;
            float bj = b1[c];
#pragma unroll
            for (int r = 0; r < 4; ++r) {
                float v = acc[t][r] + bj;
                H1s[((wave * 16 + quad * 4 + r) * 136) + c] =
                    (_Float16)(v > 0.f ? v : 0.f);
            }
        }
    }
    __syncthreads();

    // phase 2: T2 rows = (H1 · W2) · dis
    const _Float16* hp = &H1s[(wave * 16 + m16) * 136 + quad * 8];
    half8 a[4];
#pragma unroll
    for (int kk = 0; kk < 4; ++kk) a[kk] = *(const half8*)(hp + kk * 32);

    floatx4 acc[8];
#pragma unroll
    for (int t = 0; t < 8; ++t) acc[t] = (floatx4){0.f, 0.f, 0.f, 0.f};
#pragma unroll
    for (int t = 0; t < 8; ++t) {
        const _Float16* wp = W2t + (t * 16 + m16) * 128 + quad * 8;
#pragma unroll
        for (int kk = 0; kk < 4; ++kk) {
            half8 bf = *(const half8*)(wp + kk * 32);
            acc[t] = __builtin_amdgcn_mfma_f32_16x16x32_f16(a[kk], bf, acc[t], 0, 0, 0);
        }
    }
    float dis[4];
#pragma unroll
    for (int r = 0; r < 4; ++r) {
        int row = row0 + quad * 4 + r;
        dis[r] = (row < N_NODES) ? rsqrtf(1.0f + (float)ideg[row]) : 0.f;
    }
#pragma unroll
    for (int t = 0; t < 8; ++t) {
        int c = t * 16 + m16;
#pragma unroll
        for (int r = 0; r < 4; ++r) {
            int row = row0 + quad * 4 + r;
            if (row < N_NODES)
                T[(size_t)row * HID + c] = (_Float16)(acc[t][r] * dis[r]);
        }
    }
}

// FUSED gather128 + xform3: gather H2 tile to LDS, then T3 = (H2·W3)·dis (sliced out).
__global__ __launch_bounds__(256, 4) void k_g128x3(
    const int* __restrict__ cursor, const int* __restrict__ ideg,
    const int* __restrict__ col, const _Float16* __restrict__ T,
    const float* __restrict__ b2, const _Float16* __restrict__ W3t,
    _Float16* __restrict__ T3) {
    if (blockIdx.x == 0 && threadIdx.x < 16) {
        int t = threadIdx.x;
        if (t < 8) ((unsigned*)(T3 + (size_t)N_NODES * 16))[t] = 0u;
        else       ((unsigned*)(T3 + ZSL + (size_t)N_NODES * 16))[t - 8] = 0u;
    }
    __shared__ _Float16 H2s[64 * 136];

    const int lane = threadIdx.x & 63;
    const int wave = threadIdx.x >> 6;
    const int slot = lane >> 4;      // == quad
    const int fl   = lane & 15;      // == m16
    const int row0 = blockIdx.x * 64;

    float4 bb0 = *(const float4*)(b2 + fl * 8);
    float4 bb1 = *(const float4*)(b2 + fl * 8 + 4);
    float bias[8] = {bb0.x, bb0.y, bb0.z, bb0.w, bb1.x, bb1.y, bb1.z, bb1.w};

    // gather phase: wave w handles local rows [w*16, w*16+16)
    for (int k = 0; k < 16; ++k) {
        int node = row0 + wave * 16 + k;
        if (node >= N_NODES) break;
        int begin = cursor[node];
        int d     = ideg[node];
        int nb    = ((d + 31) & ~31) >> 4;
        float acc[8];
        if (slot == 0) {
            half8 v = *(const half8*)(T + (size_t)node * HID + fl * 8);
#pragma unroll
            for (int i = 0; i < 8; ++i) acc[i] = (float)v[i];
        } else {
#pragma unroll
            for (int i = 0; i < 8; ++i) acc[i] = 0.f;
        }
        const int* cp = col + begin + slot * 4;   // 16B-aligned
        for (int itb = 0; itb < nb; ++itb, cp += 16) {
            int4 cc = *(const int4*)cp;
            half8 v0 = *(const half8*)(T + (size_t)cc.x * HID + fl * 8);
            half8 v1 = *(const half8*)(T + (size_t)cc.y * HID + fl * 8);
            half8 v2 = *(const half8*)(T + (size_t)cc.z * HID + fl * 8);
            half8 v3 = *(const half8*)(T + (size_t)cc.w * HID + fl * 8);
#pragma unroll
            for (int i = 0; i < 8; ++i)
                acc[i] += ((float)v0[i] + (float)v1[i]) + ((float)v2[i] + (float)v3[i]);
        }
#pragma unroll
        for (int m = 16; m < 64; m <<= 1)
#pragma unroll
            for (int i = 0; i < 8; ++i) acc[i] += __shfl_xor(acc[i], m, 64);
        if (slot == 0) {
            float dis = rsqrtf(1.0f + (float)d);
            half8 o;
#pragma unroll
            for (int i = 0; i < 8; ++i) {
                float v = acc[i] * dis + bias[i];
                o[i] = (_Float16)(v > 0.f ? v : 0.f);
            }
            *(half8*)&H2s[(wave * 16 + k) * 136 + fl * 8] = o;
        }
    }
    __syncthreads();

    // xform3 phase: T3 rows = (H2 · W3) · dis   (m16 = fl, quad = slot)
    const _Float16* hp = &H2s[(wave * 16 + fl) * 136 + slot * 8];
    half8 a[4];
#pragma unroll
    for (int kk = 0; kk < 4; ++kk) a[kk] = *(const half8*)(hp + kk * 32);

    floatx4 acc3[2];
#pragma unroll
    for (int t = 0; t < 2; ++t) acc3[t] = (floatx4){0.f, 0.f, 0.f, 0.f};
#pragma unroll
    for (int t = 0; t < 2; ++t) {
        const _Float16* wp = W3t + (t * 16 + fl) * 128 + slot * 8;
#pragma unroll
        for (int kk = 0; kk < 4; ++kk) {
            half8 bf = *(const half8*)(wp + kk * 32);
            acc3[t] = __builtin_amdgcn_mfma_f32_16x16x32_f16(a[kk], bf, acc3[t], 0, 0, 0);
        }
    }
    float dis[4];
#pragma unroll
    for (int r = 0; r < 4; ++r) {
        int row = row0 + wave * 16 + slot * 4 + r;
        dis[r] = (row < N_NODES) ? rsqrtf(1.0f + (float)ideg[row]) : 0.f;
    }
#pragma unroll
    for (int t = 0; t < 2; ++t) {
#pragma unroll
        for (int r = 0; r < 4; ++r) {
            int row = row0 + wave * 16 + slot * 4 + r;
            if (row < N_NODES)
                T3[(size_t)t * ZSL + (size_t)row * 16 + fl] =
                    (_Float16)(acc3[t][r] * dis[r]);
        }
    }
}

// ---------------- launch ----------------

extern "C" void kernel_launch(void* const* d_in, const int* in_sizes, int n_in,
                              void* d_out, int out_size, void* d_ws, size_t ws_size,
                              hipStream_t stream) {
    const float* x  = (const float*)d_in[0];
    const int*   ei = (const int*)d_in[1];
    const float* W1 = (const float*)d_in[2];
    const float* b1 = (const float*)d_in[3];
    const float* W2 = (const float*)d_in[4];
    const float* b2 = (const float*)d_in[5];
    const float* W3 = (const float*)d_in[6];
    const float* b3 = (const float*)d_in[7];
    float* out = (float*)d_out;

    const int* src = ei;             // edge_index[0]
    const int* dst = ei + N_EDGES;   // edge_index[1]

    // workspace layout (all offsets 16B-aligned); total ~74 MB
    int*      ideg   = (int*)d_ws;                             // 102400
    int*      cursor = ideg + 102400;                          // 102400
    int*      bcur   = cursor + 102400;                        // 256
    int*      col    = bcur + 256;                             // 196*25600
    unsigned* rec    = (unsigned*)(col + NBUCK * COL_STRIDE);  // 196*9728
    _Float16* Wt     = (_Float16*)(rec + NBUCK * REC_STRIDE);  // 24576 fp16
    _Float16* t1h    = Wt + 24576;                             // 2 slices [N+1][16]
    _Float16* z      = t1h + 2 * ZSL + 16;                     // 2 slices [N+1][16]
    _Float16* T2h    = z + 2 * ZSL + 16;                       // (N+1)*128 fp16
    _Float16* T3h    = T2h + 12800128;                         // 2 slices [N+1][16]

    const int xgrid = (N_NODES + 63) / 64;   // 1563

    hipMemsetAsync(bcur, 0, 256 * sizeof(int), stream);
    k_wprep<<<96, 256, 0, stream>>>(W1, W2, W3, Wt);

    // ---- CSR build ----
    k_bucket<<<NBB, 256, 0, stream>>>(src, dst, bcur, rec);
    k_fill3p<<<NBUCK, 256, 0, stream>>>(rec, bcur, (const float2*)x,
                                        ideg, cursor, col, t1h);

    // ---- layer 1: sliced 32-dim gather, then fused MFMA 32->128->128 ----
    k_gather32_pre<<<2048, 256, 0, stream>>>(cursor, ideg, col, t1h, z);
    k_xform12<<<xgrid, 256, 0, stream>>>(z, Wt, b1, Wt + 4096, ideg, T2h);

    // ---- layer 2+3a: fused 128-dim gather + MFMA 128->32 (sliced T3 out) ----
    k_g128x3<<<xgrid, 256, 0, stream>>>(cursor, ideg, col, T2h, b2,
                                        Wt + 20480, T3h);

    // ---- layer 3b: final sliced 32-dim gather ----
    k_gather32_fin<<<2048, 256, 0, stream>>>(cursor, ideg, col, T3h, b3, out);
}

// Round 8
// 324.056 us; speedup vs baseline: 1.4247x; 1.4247x over previous
//
#include <hip/hip_runtime.h>
#include <hip/hip_fp16.h>

#define N_NODES 100000
#define N_EDGES 1600000
#define IN_F 32
#define HID 128
#define BSHIFT 9
#define BSIZE 512
#define NBUCK 196        // ceil(100000/512)
#define EPB 4096         // edges per bucket-phase block
#define NBB 391          // ceil(E/EPB)
#define REC_STRIDE 9728  // per-bucket rec capacity (mean 8163 + ~17 sigma)
#define COL_STRIDE 17408 // REC_STRIDE + 7680 (worst pad); multiple of 16

typedef _Float16 half8 __attribute__((ext_vector_type(8)));
typedef float floatx4 __attribute__((ext_vector_type(4)));

// ---------------- weight pre-transpose: W*t[n][k] fp16 in global ----------------
// Wt layout: W1t [128][32] @ 0, W2t [128][128] @ 4096, W3t [32][128] @ 20480
__global__ __launch_bounds__(256) void k_wprep(const float* __restrict__ W1,
                                               const float* __restrict__ W2,
                                               const float* __restrict__ W3,
                                               _Float16* __restrict__ Wt) {
    const int bid = blockIdx.x, t = threadIdx.x;
    if (bid < 64) {               // W2: 16384 elems
        int idx = bid * 256 + t;
        int n = idx >> 7, k = idx & 127;
        Wt[4096 + idx] = (_Float16)W2[k * HID + n];
    } else if (bid < 80) {        // W1: 4096 elems
        int idx = (bid - 64) * 256 + t;
        int n = idx >> 5, k = idx & 31;
        Wt[n * 32 + k] = (_Float16)W1[k * HID + n];
    } else {                      // W3: 4096 elems
        int idx = (bid - 80) * 256 + t;
        int n = idx >> 7, k = idx & 127;
        Wt[20480 + idx] = (_Float16)W3[k * IN_F + n];
    }
}

// ---------------- CSR build (static bucket regions; no count/scan kernels) -------

__global__ __launch_bounds__(256) void k_bucket(const int* __restrict__ src,
                                                const int* __restrict__ dst,
                                                int* __restrict__ bcur,
                                                unsigned* __restrict__ rec) {
    __shared__ int hist[256];
    __shared__ int lbase[256];
    const int e0 = blockIdx.x * EPB;
    hist[threadIdx.x] = 0;
    __syncthreads();

    unsigned rk[16]; short bk[16];
#pragma unroll
    for (int k = 0; k < 16; ++k) {
        int e = e0 + k * 256 + threadIdx.x;
        if (e < N_EDGES) {
            int d = dst[e];
            int b = d >> BSHIFT;
            bk[k] = (short)b;
            rk[k] = ((unsigned)src[e] << BSHIFT) | (unsigned)(d & (BSIZE - 1));
            atomicAdd(&hist[b], 1);
        } else bk[k] = -1;
    }
    __syncthreads();
    int c = hist[threadIdx.x];
    lbase[threadIdx.x] =
        (c > 0) ? threadIdx.x * REC_STRIDE + atomicAdd(&bcur[threadIdx.x], c) : 0;
    __syncthreads();
    hist[threadIdx.x] = 0;   // reuse as local running offset
    __syncthreads();
#pragma unroll
    for (int k = 0; k < 16; ++k) {
        if (bk[k] >= 0) {
            int off = atomicAdd(&hist[bk[k]], 1);
            rec[lbase[bk[k]] + off] = rk[k];
        }
    }
}

// per bucket: degree count + PADDED scan (rows padded to mult of 16, pads -> zero
// row N_NODES), col scatter, AND fused prescale t1 = x * dis (fp16).
__global__ __launch_bounds__(256) void k_fill3p(const unsigned* __restrict__ rec,
                                                const int* __restrict__ bcur,
                                                const float2* __restrict__ x2,
                                                int* __restrict__ ideg,
                                                int* __restrict__ cursor,
                                                int* __restrict__ col,
                                                __half2* __restrict__ t1) {
    __shared__ int lcnt[BSIZE];
    __shared__ int lcur[BSIZE];
    __shared__ int lend[BSIZE];
    __shared__ int s[256];
    const int b = blockIdx.x;
    const int t = threadIdx.x;
    const int n0 = b << BSHIFT;
    const int rbeg = b * REC_STRIDE;
    const int rend = rbeg + bcur[b];
    const int pbeg = b * COL_STRIDE;   // 16-aligned

    lcnt[t] = 0;
    lcnt[t + 256] = 0;
    __syncthreads();
    for (int i = rbeg + t; i < rend; i += 256)
        atomicAdd(&lcnt[rec[i] & (BSIZE - 1)], 1);
    __syncthreads();

    int a0 = lcnt[2 * t], a1 = lcnt[2 * t + 1];
    int p0 = (a0 + 15) & ~15, p1 = (a1 + 15) & ~15;
    int pv = p0 + p1;
    s[t] = pv;
    __syncthreads();
    for (int off = 1; off < 256; off <<= 1) {
        int v = (t >= off) ? s[t - off] : 0;
        __syncthreads();
        s[t] += v;
        __syncthreads();
    }
    int ex = s[t] - pv;
    int c0 = pbeg + ex;
    int c1 = c0 + p0;
    lcur[2 * t]     = c0;  lend[2 * t]     = c0 + p0;
    lcur[2 * t + 1] = c1;  lend[2 * t + 1] = c1 + p1;
    __syncthreads();

    for (int i = t; i < BSIZE; i += 256) {
        int n = n0 + i;
        if (n < N_NODES) {
            ideg[n]   = lcnt[i];
            cursor[n] = lcur[i];
        }
    }
    __syncthreads();
    for (int i = rbeg + t; i < rend; i += 256) {
        unsigned r = rec[i];
        int slot = atomicAdd(&lcur[r & (BSIZE - 1)], 1);
        col[slot] = (int)(r >> BSHIFT);
    }
    __syncthreads();
    for (int i = t; i < BSIZE; i += 256) {
        int e2 = lend[i];
        for (int k = lcur[i]; k < e2; ++k) col[k] = N_NODES;
    }

    // fused prescale for this bucket's 512 nodes (+ zero row by block 0)
    if (b == 0 && t < 16) ((unsigned*)t1)[N_NODES * 16 + t] = 0u;
    for (int idx = t; idx < BSIZE * 16; idx += 256) {
        int loc = idx >> 4, j = idx & 15;
        int n = n0 + loc;
        if (n < N_NODES) {
            float dis = rsqrtf(1.0f + (float)lcnt[loc]);
            float2 v = x2[(size_t)n * 16 + j];
            t1[(size_t)n * 16 + j] = __floats2half2_rn(v.x * dis, v.y * dis);
        }
    }
}

// ---------------- gathers (branch-free padded CSR, static partition) ----------------

// pre: z = acc*dis, fp16 out. 16 slots x 4 feat-lanes, x2-deep pipeline.
__global__ __launch_bounds__(256) void k_gather32_pre(
    const int* __restrict__ cursor, const int* __restrict__ ideg,
    const int* __restrict__ col, const _Float16* __restrict__ T,
    _Float16* __restrict__ OUT) {
    const int lane = threadIdx.x & 63;
    const int slot = lane >> 2;
    const int fl   = lane & 3;
    const int wid  = blockIdx.x * 4 + (threadIdx.x >> 6);
    const int wstride = gridDim.x * 4;

    for (int node = wid; node < N_NODES; node += wstride) {
        int begin = cursor[node];
        int d     = ideg[node];
        int nb    = (d + 15) >> 4;
        float acc[8];
        if (slot == 0) {
            half8 v = *(const half8*)(T + (size_t)node * IN_F + fl * 8);
#pragma unroll
            for (int i = 0; i < 8; ++i) acc[i] = (float)v[i];
        } else {
#pragma unroll
            for (int i = 0; i < 8; ++i) acc[i] = 0.f;
        }
        const int* cp = col + begin + slot;
        int itb = 0;
        for (; itb + 2 <= nb; itb += 2, cp += 32) {
            int s0 = cp[0];
            int s1 = cp[16];
            half8 v0 = *(const half8*)(T + (size_t)s0 * IN_F + fl * 8);
            half8 v1 = *(const half8*)(T + (size_t)s1 * IN_F + fl * 8);
#pragma unroll
            for (int i = 0; i < 8; ++i) acc[i] += (float)v0[i] + (float)v1[i];
        }
        if (itb < nb) {
            int s0 = cp[0];
            half8 v0 = *(const half8*)(T + (size_t)s0 * IN_F + fl * 8);
#pragma unroll
            for (int i = 0; i < 8; ++i) acc[i] += (float)v0[i];
        }
#pragma unroll
        for (int m = 4; m < 64; m <<= 1)
#pragma unroll
            for (int i = 0; i < 8; ++i) acc[i] += __shfl_xor(acc[i], m, 64);
        if (slot == 0) {
            float dis = rsqrtf(1.0f + (float)d);
            half8 o;
#pragma unroll
            for (int i = 0; i < 8; ++i) o[i] = (_Float16)(acc[i] * dis);
            *(half8*)(OUT + (size_t)node * IN_F + fl * 8) = o;
        }
    }
}

// fin: out = relu(acc*dis + b), fp32 out
__global__ __launch_bounds__(256) void k_gather32_fin(
    const int* __restrict__ cursor, const int* __restrict__ ideg,
    const int* __restrict__ col, const _Float16* __restrict__ T,
    const float* __restrict__ b, float* __restrict__ OUT) {
    const int lane = threadIdx.x & 63;
    const int slot = lane >> 2;
    const int fl   = lane & 3;
    const int wid  = blockIdx.x * 4 + (threadIdx.x >> 6);
    const int wstride = gridDim.x * 4;

    float4 bb0 = *(const float4*)(b + fl * 8);
    float4 bb1 = *(const float4*)(b + fl * 8 + 4);
    float bias[8] = {bb0.x, bb0.y, bb0.z, bb0.w, bb1.x, bb1.y, bb1.z, bb1.w};

    for (int node = wid; node < N_NODES; node += wstride) {
        int begin = cursor[node];
        int d     = ideg[node];
        int nb    = (d + 15) >> 4;
        float acc[8];
        if (slot == 0) {
            half8 v = *(const half8*)(T + (size_t)node * IN_F + fl * 8);
#pragma unroll
            for (int i = 0; i < 8; ++i) acc[i] = (float)v[i];
        } else {
#pragma unroll
            for (int i = 0; i < 8; ++i) acc[i] = 0.f;
        }
        const int* cp = col + begin + slot;
        int itb = 0;
        for (; itb + 2 <= nb; itb += 2, cp += 32) {
            int s0 = cp[0];
            int s1 = cp[16];
            half8 v0 = *(const half8*)(T + (size_t)s0 * IN_F + fl * 8);
            half8 v1 = *(const half8*)(T + (size_t)s1 * IN_F + fl * 8);
#pragma unroll
            for (int i = 0; i < 8; ++i) acc[i] += (float)v0[i] + (float)v1[i];
        }
        if (itb < nb) {
            int s0 = cp[0];
            half8 v0 = *(const half8*)(T + (size_t)s0 * IN_F + fl * 8);
#pragma unroll
            for (int i = 0; i < 8; ++i) acc[i] += (float)v0[i];
        }
#pragma unroll
        for (int m = 4; m < 64; m <<= 1)
#pragma unroll
            for (int i = 0; i < 8; ++i) acc[i] += __shfl_xor(acc[i], m, 64);
        if (slot == 0) {
            float dis = rsqrtf(1.0f + (float)d);
            float o[8];
#pragma unroll
            for (int i = 0; i < 8; ++i) {
                float v = acc[i] * dis + bias[i];
                o[i] = v > 0.f ? v : 0.f;
            }
            float* op = OUT + (size_t)node * IN_F + fl * 8;
            *(float4*)op       = make_float4(o[0], o[1], o[2], o[3]);
            *(float4*)(op + 4) = make_float4(o[4], o[5], o[6], o[7]);
        }
    }
}

// ---------------- MFMA transforms ----------------
// 16x16x32 layouts: A[m=lane&15][k=quad*8+j], B[k=quad*8+j][n=lane&15],
// D[row=quad*4+r][col=lane&15]. Block = 4 waves x 16 rows = 64 rows.

// FUSED layers 1+2 transform: T2 = (relu(z·W1 + b1) · W2) · dis.
// Weights read as fragments from pre-transposed global (L1/L2-hot); LDS = H1 tile only.
__global__ __launch_bounds__(256, 4) void k_xform12(
    const _Float16* __restrict__ z, const _Float16* __restrict__ W1t,
    const float* __restrict__ b1, const _Float16* __restrict__ W2t,
    const int* __restrict__ ideg, _Float16* __restrict__ T) {
    if (blockIdx.x == 0 && threadIdx.x < 64)
        ((unsigned*)(T + (size_t)N_NODES * HID))[threadIdx.x] = 0u;
    __shared__ _Float16 H1s[64 * 136];

    const int lane = threadIdx.x & 63;
    const int wave = threadIdx.x >> 6;
    const int m16 = lane & 15, quad = lane >> 4;
    const int row0 = blockIdx.x * 64 + wave * 16;
    if (row0 >= N_NODES) return;

    // phase 1: H1 tile = relu(z·W1 + b1)
    {
        int arow = row0 + m16; if (arow >= N_NODES) arow = N_NODES - 1;
        half8 a = *(const half8*)(z + (size_t)arow * IN_F + quad * 8);
        floatx4 acc[8];
#pragma unroll
        for (int t = 0; t < 8; ++t) acc[t] = (floatx4){0.f, 0.f, 0.f, 0.f};
#pragma unroll
        for (int t = 0; t < 8; ++t) {
            half8 bf = *(const half8*)(W1t + (t * 16 + m16) * 32 + quad * 8);
            acc[t] = __builtin_amdgcn_mfma_f32_16x16x32_f16(a, bf, acc[t], 0, 0, 0);
        }
#pragma unroll
        for (int t = 0; t < 8; ++t) {
            int c = t * 16 + m16;
            float bj = b1[c];
#pragma unroll
            for (int r = 0; r < 4; ++r) {
                float v = acc[t][r] + bj;
                H1s[((wave * 16 + quad * 4 + r) * 136) + c] =
                    (_Float16)(v > 0.f ? v : 0.f);
            }
        }
    }
    __syncthreads();

    // phase 2: T2 rows = (H1 · W2) · dis
    const _Float16* hp = &H1s[(wave * 16 + m16) * 136 + quad * 8];
    half8 a[4];
#pragma unroll
    for (int kk = 0; kk < 4; ++kk) a[kk] = *(const half8*)(hp + kk * 32);

    floatx4 acc[8];
#pragma unroll
    for (int t = 0; t < 8; ++t) acc[t] = (floatx4){0.f, 0.f, 0.f, 0.f};
#pragma unroll
    for (int t = 0; t < 8; ++t) {
        const _Float16* wp = W2t + (t * 16 + m16) * 128 + quad * 8;
#pragma unroll
        for (int kk = 0; kk < 4; ++kk) {
            half8 bf = *(const half8*)(wp + kk * 32);
            acc[t] = __builtin_amdgcn_mfma_f32_16x16x32_f16(a[kk], bf, acc[t], 0, 0, 0);
        }
    }
    float dis[4];
#pragma unroll
    for (int r = 0; r < 4; ++r) {
        int row = row0 + quad * 4 + r;
        dis[r] = (row < N_NODES) ? rsqrtf(1.0f + (float)ideg[row]) : 0.f;
    }
#pragma unroll
    for (int t = 0; t < 8; ++t) {
        int c = t * 16 + m16;
#pragma unroll
        for (int r = 0; r < 4; ++r) {
            int row = row0 + quad * 4 + r;
            if (row < N_NODES)
                T[(size_t)row * HID + c] = (_Float16)(acc[t][r] * dis[r]);
        }
    }
}

// FUSED gather128 + xform3: per 64-node tile, gather H2 rows (relu(acc*dis+b2))
// into LDS, then T3 = (H2 · W3) · dis. 8 blocks/CU (LDS 17.4KB x 8 = 139KB).
__global__ __launch_bounds__(256, 8) void k_g128x3(
    const int* __restrict__ cursor, const int* __restrict__ ideg,
    const int* __restrict__ col, const _Float16* __restrict__ T,
    const float* __restrict__ b2, const _Float16* __restrict__ W3t,
    _Float16* __restrict__ T3) {
    if (blockIdx.x == 0 && threadIdx.x < 16)
        ((unsigned*)(T3 + (size_t)N_NODES * IN_F))[threadIdx.x] = 0u;
    __shared__ _Float16 H2s[64 * 136];

    const int lane = threadIdx.x & 63;
    const int wave = threadIdx.x >> 6;
    const int slot = lane >> 4;      // == quad
    const int fl   = lane & 15;      // == m16
    const int row0 = blockIdx.x * 64;

    float4 bb0 = *(const float4*)(b2 + fl * 8);
    float4 bb1 = *(const float4*)(b2 + fl * 8 + 4);
    float bias[8] = {bb0.x, bb0.y, bb0.z, bb0.w, bb1.x, bb1.y, bb1.z, bb1.w};

    // gather phase: wave w handles local rows [w*16, w*16+16)
    for (int k = 0; k < 16; ++k) {
        int node = row0 + wave * 16 + k;
        if (node >= N_NODES) break;
        int begin = cursor[node];
        int d     = ideg[node];
        int nb    = (d + 15) >> 4;
        float acc[8];
        if (slot == 0) {
            half8 v = *(const half8*)(T + (size_t)node * HID + fl * 8);
#pragma unroll
            for (int i = 0; i < 8; ++i) acc[i] = (float)v[i];
        } else {
#pragma unroll
            for (int i = 0; i < 8; ++i) acc[i] = 0.f;
        }
        const int* cp = col + begin + slot * 4;   // 16B-aligned
        for (int itb = 0; itb < nb; ++itb, cp += 16) {
            int4 cc = *(const int4*)cp;
            half8 v0 = *(const half8*)(T + (size_t)cc.x * HID + fl * 8);
            half8 v1 = *(const half8*)(T + (size_t)cc.y * HID + fl * 8);
            half8 v2 = *(const half8*)(T + (size_t)cc.z * HID + fl * 8);
            half8 v3 = *(const half8*)(T + (size_t)cc.w * HID + fl * 8);
#pragma unroll
            for (int i = 0; i < 8; ++i)
                acc[i] += ((float)v0[i] + (float)v1[i]) + ((float)v2[i] + (float)v3[i]);
        }
#pragma unroll
        for (int m = 16; m < 64; m <<= 1)
#pragma unroll
            for (int i = 0; i < 8; ++i) acc[i] += __shfl_xor(acc[i], m, 64);
        if (slot == 0) {
            float dis = rsqrtf(1.0f + (float)d);
            half8 o;
#pragma unroll
            for (int i = 0; i < 8; ++i) {
                float v = acc[i] * dis + bias[i];
                o[i] = (_Float16)(v > 0.f ? v : 0.f);
            }
            *(half8*)&H2s[(wave * 16 + k) * 136 + fl * 8] = o;
        }
    }
    __syncthreads();

    // xform3 phase: T3 rows = (H2 · W3) · dis   (m16 = fl, quad = slot)
    const _Float16* hp = &H2s[(wave * 16 + fl) * 136 + slot * 8];
    half8 a[4];
#pragma unroll
    for (int kk = 0; kk < 4; ++kk) a[kk] = *(const half8*)(hp + kk * 32);

    floatx4 acc3[2];
#pragma unroll
    for (int t = 0; t < 2; ++t) acc3[t] = (floatx4){0.f, 0.f, 0.f, 0.f};
#pragma unroll
    for (int t = 0; t < 2; ++t) {
        const _Float16* wp = W3t + (t * 16 + fl) * 128 + slot * 8;
#pragma unroll
        for (int kk = 0; kk < 4; ++kk) {
            half8 bf = *(const half8*)(wp + kk * 32);
            acc3[t] = __builtin_amdgcn_mfma_f32_16x16x32_f16(a[kk], bf, acc3[t], 0, 0, 0);
        }
    }
    float dis[4];
#pragma unroll
    for (int r = 0; r < 4; ++r) {
        int row = row0 + wave * 16 + slot * 4 + r;
        dis[r] = (row < N_NODES) ? rsqrtf(1.0f + (float)ideg[row]) : 0.f;
    }
#pragma unroll
    for (int t = 0; t < 2; ++t) {
        int c = t * 16 + fl;
#pragma unroll
        for (int r = 0; r < 4; ++r) {
            int row = row0 + wave * 16 + slot * 4 + r;
            if (row < N_NODES)
                T3[(size_t)row * IN_F + c] = (_Float16)(acc3[t][r] * dis[r]);
        }
    }
}

// ---------------- launch ----------------

extern "C" void kernel_launch(void* const* d_in, const int* in_sizes, int n_in,
                              void* d_out, int out_size, void* d_ws, size_t ws_size,
                              hipStream_t stream) {
    const float* x  = (const float*)d_in[0];
    const int*   ei = (const int*)d_in[1];
    const float* W1 = (const float*)d_in[2];
    const float* b1 = (const float*)d_in[3];
    const float* W2 = (const float*)d_in[4];
    const float* b2 = (const float*)d_in[5];
    const float* W3 = (const float*)d_in[6];
    const float* b3 = (const float*)d_in[7];
    float* out = (float*)d_out;

    const int* src = ei;             // edge_index[0]
    const int* dst = ei + N_EDGES;   // edge_index[1]

    // workspace layout (all offsets 16B-aligned); total ~67 MB
    int*      ideg   = (int*)d_ws;                             // 102400
    int*      cursor = ideg + 102400;                          // 102400
    int*      bcur   = cursor + 102400;                        // 256
    int*      col    = bcur + 256;                             // 196*17408
    unsigned* rec    = (unsigned*)(col + NBUCK * COL_STRIDE);  // 196*9728
    _Float16* Wt     = (_Float16*)(rec + NBUCK * REC_STRIDE);  // 24576 fp16
    _Float16* t1h    = Wt + 24576;                             // (N+1)*32 fp16
    _Float16* z      = t1h + 3200064;                          // N*32 fp16
    _Float16* T2h    = z + 3200064;                            // (N+1)*128 fp16
    _Float16* T3h    = T2h + 12800128;                         // (N+1)*32 fp16

    const int xgrid = (N_NODES + 63) / 64;   // 1563

    hipMemsetAsync(bcur, 0, 256 * sizeof(int), stream);
    k_wprep<<<96, 256, 0, stream>>>(W1, W2, W3, Wt);

    // ---- CSR build ----
    k_bucket<<<NBB, 256, 0, stream>>>(src, dst, bcur, rec);
    k_fill3p<<<NBUCK, 256, 0, stream>>>(rec, bcur, (const float2*)x,
                                        ideg, cursor, col, (__half2*)t1h);

    // ---- layer 1: 32-dim gather, then fused MFMA 32->128->128 ----
    k_gather32_pre<<<2048, 256, 0, stream>>>(cursor, ideg, col, t1h, z);
    k_xform12<<<xgrid, 256, 0, stream>>>(z, Wt, b1, Wt + 4096, ideg, T2h);

    // ---- layer 2+3a: fused 128-dim gather + MFMA 128->32 ----
    k_g128x3<<<xgrid, 256, 0, stream>>>(cursor, ideg, col, T2h, b2,
                                        Wt + 20480, T3h);

    // ---- layer 3b: final 32-dim gather ----
    k_gather32_fin<<<2048, 256, 0, stream>>>(cursor, ideg, col, T3h, b3, out);
}